// Round 6
// baseline (187.413 us; speedup 1.0000x reference)
//
#include <hip/hip_runtime.h>
#include <math.h>

typedef unsigned short ushort_t;
typedef __bf16 v8bf __attribute__((ext_vector_type(8)));
typedef __bf16 v4bf __attribute__((ext_vector_type(4)));
typedef float  v4f  __attribute__((ext_vector_type(4)));
typedef float  f32x4 __attribute__((ext_vector_type(4)));

#define BATCH 4
#define SEQ 4096
#define DM 1024
#define NS 256
#define MROWS (BATCH*SEQ)   // 16384

#define NCH 128
#define CL (SEQ/NCH)        // 32

#define BK1 64              // gemm1 K-step
#define BM2 32              // gemm2 rows/block = 1 scan chunk

typedef __attribute__((address_space(1))) void as1_void;
typedef __attribute__((address_space(3))) void as3_void;

__device__ __forceinline__ void gl_lds16(const void* g, void* l) {
    __builtin_amdgcn_global_load_lds((as1_void*)g, (as3_void*)l, 16, 0, 0);
}

__device__ __forceinline__ ushort_t f2bf(float f) {
    unsigned u = __builtin_bit_cast(unsigned, f);
    u += 0x7fff + ((u >> 16) & 1);          // RNE
    return (ushort_t)(u >> 16);
}

__device__ __forceinline__ float sigm(float x) { return 1.0f / (1.0f + expf(-x)); }

__device__ __forceinline__ float powk(int e, float l1, float l2, float l4,
                                      float l8, float l16) {
    float w = 1.0f;
    if (e & 1)  w *= l1;
    if (e & 2)  w *= l2;
    if (e & 4)  w *= l4;
    if (e & 8)  w *= l8;
    if (e & 16) w *= l16;
    return w;
}

// ---------------------------------------------------------------------------
// GEMM1 (full-K): Bu = u . B_w^T, tile 32(m) x 256(n), BK=64.
// A: fp32 global -> regs (2-deep prefetch) -> bf16 swizzled ds_write into an
//    8 KB double buffer (only LDS in the kernel).
// B: NO LDS staging -- B-fragments load DIRECT from L2-resident Bw16 into
//    registers (per-lane 16B at row(fr)*K + fq*8; 16 x 64B segments/instr).
// The per-iter barrier now guards only the 4 KB A ds_write; no heavy
// vmcnt(0) staging drain. grid 512 = 2 blocks/CU. cf computed in-register.
// ---------------------------------------------------------------------------
__global__ __launch_bounds__(256)
void gemm1_fused(const float* __restrict__ A,      // u [M,K] fp32
                 const ushort_t* __restrict__ B,   // Bw16 [NS,K] bf16
                 float* __restrict__ Bu,           // [M,NS] fp32
                 const float* __restrict__ ll,     // [NS]
                 float* __restrict__ cf)           // [BATCH,NCH,NS]
{
    const int K = DM;
    __shared__ __align__(16) ushort_t As[2][32*BK1];    // 2 x 4 KB

    const int tid  = threadIdx.x;
    const int lane = tid & 63;
    const int wave = tid >> 6;       // n-quadrant: cols wave*64..wave*64+63
    const int m0   = blockIdx.x * 32;

    const int fr = lane & 15;
    const int fq = lane >> 4;

    // A staging: 32x64 fp32 = 512 float4 chunks, 2/thread; swizzled ds_write.
    int arow[2], ac4[2], aoff[2];
    #pragma unroll
    for (int j = 0; j < 2; ++j) {
        int cid = j*256 + tid;
        arow[j] = cid >> 4;
        ac4[j]  = (cid & 15) * 4;
        aoff[j] = arow[j]*BK1 + (((ac4[j] >> 3) ^ (arow[j] & 7)) * 8) + (ac4[j] & 4);
    }

    f32x4 acc[2][4] = {};   // [mi][ni] : m = mi*16.., n = wave*64 + ni*16..
    v4f areg0[2], areg1[2];

    const int NIT = K / BK1;   // 16 (even)

    // per-lane B fragment base: row = wave*64 + fr, k-offset fq*8
    const ushort_t* Bq = B + (size_t)(wave*64 + fr)*K + fq*8;

    // ---- prologue: A k=0, A k=1 ----
    #pragma unroll
    for (int j = 0; j < 2; ++j)
        areg0[j] = *(const v4f*)&A[(size_t)(m0 + arow[j])*K + ac4[j]];
    #pragma unroll
    for (int j = 0; j < 2; ++j)
        areg1[j] = *(const v4f*)&A[(size_t)(m0 + arow[j])*K + BK1 + ac4[j]];

    // one step per macro call; P = LDS buffer parity (compile-time)
    #define G1_STEP(IT, P, AREG)                                               \
    {                                                                          \
        _Pragma("unroll")                                                      \
        for (int j = 0; j < 2; ++j)                                            \
            *(v4bf*)&As[P][aoff[j]] = __builtin_convertvector(AREG[j], v4bf);  \
        __syncthreads();                                                       \
        if ((IT) + 2 < NIT) {                                                  \
            const int k2 = ((IT) + 2) * BK1;                                   \
            _Pragma("unroll")                                                  \
            for (int j = 0; j < 2; ++j)                                        \
                AREG[j] = *(const v4f*)&A[(size_t)(m0 + arow[j])*K + k2 + ac4[j]]; \
        }                                                                      \
        _Pragma("unroll")                                                      \
        for (int kk = 0; kk < 2; ++kk) {                                       \
            v8bf af[2], bf[4];                                                 \
            _Pragma("unroll")                                                  \
            for (int mi = 0; mi < 2; ++mi) {                                   \
                const int r  = mi*16 + fr;                                     \
                const int ch = (kk*4 + fq) ^ (r & 7);                          \
                af[mi] = *reinterpret_cast<const v8bf*>(&As[P][r*BK1 + ch*8]); \
            }                                                                  \
            _Pragma("unroll")                                                  \
            for (int ni = 0; ni < 4; ++ni)                                     \
                bf[ni] = *reinterpret_cast<const v8bf*>(                       \
                    &Bq[(size_t)ni*16*K + (IT)*BK1 + kk*32]);                  \
            _Pragma("unroll")                                                  \
            for (int mi = 0; mi < 2; ++mi)                                     \
                _Pragma("unroll")                                              \
                for (int ni = 0; ni < 4; ++ni)                                 \
                    acc[mi][ni] = __builtin_amdgcn_mfma_f32_16x16x32_bf16(     \
                                      af[mi], bf[ni], acc[mi][ni], 0, 0, 0);   \
        }                                                                      \
    }

    for (int it = 0; it < NIT; it += 2) {
        G1_STEP(it,     0, areg0);
        G1_STEP(it + 1, 1, areg1);
    }
    #undef G1_STEP

    // ---- write Bu. C/D layout: col=lane&15, row=(lane>>4)*4+reg ----
    #pragma unroll
    for (int mi = 0; mi < 2; ++mi) {
        #pragma unroll
        for (int ni = 0; ni < 4; ++ni) {
            const int col = wave*64 + ni*16 + fr;
            #pragma unroll
            for (int r = 0; r < 4; ++r)
                Bu[(size_t)(m0 + mi*16 + fq*4 + r)*NS + col] = acc[mi][ni][r];
        }
    }

    // ---- chunk final: cf[b,c,n] = sum_t lam^(31-t) Bu[t,n]; block = chunk ----
    const int b_idx = m0 >> 12;            // 4096 rows per batch
    const int c_idx = (m0 & 4095) >> 5;    // 32 rows per chunk

    #pragma unroll
    for (int ni = 0; ni < 4; ++ni) {
        const int col = wave*64 + ni*16 + fr;
        const float l1  = sigm(ll[col]);
        const float l2  = l1*l1;
        const float l4  = l2*l2;
        const float l8  = l4*l4;
        const float l16 = l8*l8;
        float f = 0.0f;
        #pragma unroll
        for (int mi = 0; mi < 2; ++mi) {
            float w = powk(28 - mi*16 - fq*4, l1, l2, l4, l8, l16);
            f = fmaf(w, acc[mi][ni][3], f);
            w *= l1; f = fmaf(w, acc[mi][ni][2], f);
            w *= l1; f = fmaf(w, acc[mi][ni][1], f);
            w *= l1; f = fmaf(w, acc[mi][ni][0], f);
        }
        f += __shfl_xor(f, 16, 64);
        f += __shfl_xor(f, 32, 64);
        if (fq == 0)
            cf[((size_t)b_idx*NCH + c_idx)*NS + col] = f;
    }
}

// ---------------------------------------------------------------------------
// GEMM2+scan fused, 32-row blocks (1 chunk), 256 thr, grid 512 = 2 blocks/CU.
//   1) v[32] = Bu column (coalesced) -> regs; carry Horner over cf (L2);
//      scan replay -> swizzled bf16 hs in LDS (16 KB). ONE barrier.
//   2) GEMM vs L2-resident Cw16 with DIRECT register B-fragment gathers —
//      no LDS staging, zero barriers in the whole K/N loop.
// Wave tile: 32 rows x 256 cols, processed as 4 slabs of 64 cols.
// ---------------------------------------------------------------------------
__global__ __launch_bounds__(256)
void gemm2_scan(const float* __restrict__ Bu,     // [M,NS] fp32
                const ushort_t* __restrict__ Cw,  // Cw16 [DM,NS] bf16
                const float* __restrict__ ll,     // [NS]
                const float* __restrict__ cf,     // [BATCH,NCH,NS]
                float* __restrict__ Y,            // [M,DM] fp32
                const float* __restrict__ Dvec,
                const float* __restrict__ U)
{
    __shared__ __align__(16) ushort_t hsS[BM2*NS];        // 16 KB (swizzled)

    const int tid  = threadIdx.x;
    const int lane = tid & 63;
    const int wave = tid >> 6;       // y-col quarter: cols wave*256..+255
    const int fr = lane & 15;
    const int fq = lane >> 4;
    const int m0 = blockIdx.x * BM2;
    const int n  = tid;              // state column 0..255

    // ---- 1) Bu column -> regs (issued first; 32 coalesced rows) ----
    const float* bp = Bu + (size_t)m0*NS + n;
    float v[CL];
    #pragma unroll
    for (int t = 0; t < CL; ++t)
        v[t] = bp[(size_t)t*NS];

    // ---- carry Horner over cf ----
    const int b_idx = m0 >> 12;
    const int cG    = (m0 & 4095) >> 5;    // need chunks [0, cG)
    const float lam = sigm(ll[n]);
    float lamL = lam;
    #pragma unroll
    for (int i = 0; i < 5; ++i) lamL *= lamL;   // lam^32

    const float* cfb = cf + (size_t)b_idx*NCH*NS + n;
    float x = 0.0f;
    int cc = 0;
    for (; cc + 16 <= cG; cc += 16) {
        float vv[16];
        #pragma unroll
        for (int j = 0; j < 16; ++j) vv[j] = cfb[(size_t)(cc + j)*NS];
        #pragma unroll
        for (int j = 0; j < 16; ++j) x = fmaf(lamL, x, vv[j]);
    }
    for (; cc < cG; ++cc) x = fmaf(lamL, x, cfb[(size_t)cc*NS]);

    // ---- scan replay; hs written bf16 with (row&7) chunk-XOR swizzle ----
    float h = x;
    #pragma unroll
    for (int t = 0; t < CL; ++t) {
        h = fmaf(lam, h, v[t]);
        hsS[t*NS + (((n >> 3) ^ (t & 7)) << 3) + (n & 7)] = f2bf(h);
    }
    __syncthreads();   // the ONLY barrier

    // ---- 2) GEMM, barrier-free: 4 slabs x (K=256 in 8 k-steps of 32) ----
    // per-lane Cw fragment base: row (y-col) = wave*256 + fr, k-offset fq*8
    const ushort_t* Cq = Cw + (size_t)(wave*256 + fr)*NS + fq*8;

    for (int sl = 0; sl < 4; ++sl) {
        f32x4 acc[2][4] = {};
        #pragma unroll
        for (int kk = 0; kk < 8; ++kk) {
            v8bf af[2], bf[4];
            #pragma unroll
            for (int mi = 0; mi < 2; ++mi) {
                const int r  = mi*16 + fr;
                const int ch = (kk*4 + fq) ^ (r & 7);
                af[mi] = *reinterpret_cast<const v8bf*>(&hsS[r*NS + ch*8]);
            }
            #pragma unroll
            for (int ni = 0; ni < 4; ++ni)
                bf[ni] = *reinterpret_cast<const v8bf*>(
                    &Cq[(size_t)(sl*64 + ni*16)*NS + kk*32]);
            #pragma unroll
            for (int mi = 0; mi < 2; ++mi)
                #pragma unroll
                for (int ni = 0; ni < 4; ++ni)
                    acc[mi][ni] = __builtin_amdgcn_mfma_f32_16x16x32_bf16(
                                      af[mi], bf[ni], acc[mi][ni], 0, 0, 0);
        }
        // slab epilogue (C/D layout: col=lane&15, row=fq*4+reg)
        #pragma unroll
        for (int ni = 0; ni < 4; ++ni) {
            const int gcol = wave*256 + sl*64 + ni*16 + fr;
            const float d = Dvec[gcol];
            #pragma unroll
            for (int mi = 0; mi < 2; ++mi) {
                #pragma unroll
                for (int r = 0; r < 4; ++r) {
                    const int grow = m0 + mi*16 + fq*4 + r;
                    const size_t idx = (size_t)grow*DM + gcol;
                    float vo = acc[mi][ni][r];
                    if (d != 0.0f) vo = fmaf(d, U[idx], vo);   // no load when D==0
                    Y[idx] = vo;
                }
            }
        }
    }
}

// ---------------------------------------------------------------------------
__global__ __launch_bounds__(256)
void cvt_w(const float4* __restrict__ Bw, const float4* __restrict__ Cw,
           ushort_t* __restrict__ Bo, ushort_t* __restrict__ Co)
{
    const int i = blockIdx.x * 256 + threadIdx.x;
    const float4* src = blockIdx.y ? Cw : Bw;
    ushort_t*     dst = blockIdx.y ? Co : Bo;
    float4 v = src[i];
    ushort4 o;
    o.x = f2bf(v.x); o.y = f2bf(v.y); o.z = f2bf(v.z); o.w = f2bf(v.w);
    *(ushort4*)&dst[4*(size_t)i] = o;
}

// ---------------------------------------------------------------------------
extern "C" void kernel_launch(void* const* d_in, const int* in_sizes, int n_in,
                              void* d_out, int out_size, void* d_ws, size_t ws_size,
                              hipStream_t stream) {
    const float* u          = (const float*)d_in[0];
    const float* log_lambda = (const float*)d_in[1];
    const float* B_w        = (const float*)d_in[2];
    const float* C_w        = (const float*)d_in[3];
    const float* Dv         = (const float*)d_in[4];
    float* y  = (float*)d_out;

    char* w = (char*)d_ws;
    float*    Bu   = (float*)w;                        // 16.78 MB
    ushort_t* Bw16 = (ushort_t*)(w + 16777216);        // 512 KB
    ushort_t* Cw16 = (ushort_t*)(w + 17301504);        // 512 KB
    float*    cf   = (float*)(w + 17825792);           // 512 KB

    dim3 blk(256);

    // 0) weight conversions
    cvt_w<<<dim3(256, 2), blk, 0, stream>>>((const float4*)B_w, (const float4*)C_w,
                                            Bw16, Cw16);

    // 1) Bu = u . B_w^T (A LDS-staged, B direct-from-L2), fused chunk finals
    gemm1_fused<<<dim3(MROWS/32), blk, 0, stream>>>(u, Bw16, Bu, log_lambda, cf);

    // 2) fused scan + y = hs . C_w^T + D*u (Cw direct-from-L2, 1 barrier)
    gemm2_scan<<<dim3(MROWS/BM2), blk, 0, stream>>>(
        Bu, Cw16, log_lambda, cf, y, Dv, u);
}

// Round 8
// 169.210 us; speedup vs baseline: 1.1076x; 1.1076x over previous
//
#include <hip/hip_runtime.h>
#include <math.h>

typedef unsigned short ushort_t;
typedef __bf16 v8bf __attribute__((ext_vector_type(8)));
typedef __bf16 v4bf __attribute__((ext_vector_type(4)));
typedef float  v4f  __attribute__((ext_vector_type(4)));
typedef float  f32x4 __attribute__((ext_vector_type(4)));

#define BATCH 4
#define SEQ 4096
#define DM 1024
#define NS 256
#define MROWS (BATCH*SEQ)   // 16384

#define NCH 128
#define CL (SEQ/NCH)        // 32

#define BK1 64              // gemm1 K-step
#define BN1 128             // gemm1 cols/block (N-split for 4 blocks/CU)
#define BM2 32              // gemm2 rows/block = 1 scan chunk
#define BK2 64              // gemm2 K-step

typedef __attribute__((address_space(1))) void as1_void;
typedef __attribute__((address_space(3))) void as3_void;

__device__ __forceinline__ void gl_lds16(const void* g, void* l) {
    __builtin_amdgcn_global_load_lds((as1_void*)g, (as3_void*)l, 16, 0, 0);
}

__device__ __forceinline__ ushort_t f2bf(float f) {
    unsigned u = __builtin_bit_cast(unsigned, f);
    u += 0x7fff + ((u >> 16) & 1);          // RNE
    return (ushort_t)(u >> 16);
}

__device__ __forceinline__ float sigm(float x) { return 1.0f / (1.0f + expf(-x)); }

__device__ __forceinline__ float powk(int e, float l1, float l2, float l4,
                                      float l8, float l16) {
    float w = 1.0f;
    if (e & 1)  w *= l1;
    if (e & 2)  w *= l2;
    if (e & 4)  w *= l4;
    if (e & 8)  w *= l8;
    if (e & 16) w *= l16;
    return w;
}

// ---------------------------------------------------------------------------
// GEMM1 (full-K): Bu = u . B_w^T, tile 32(m) x 128(n), BK=64, double-buffered,
// XOR-swizzled LDS, 2-deep A prefetch (named areg0/areg1). N split in 2 so
// LDS = 40 KB -> 4 blocks/CU = 16 waves/CU (TLP to hide the barrier drain;
// every pipe idle at 2 blocks/CU was the round-3..6 bottleneck). u rows are
// read by 2 blocks (L3-resident, cheap). grid (2, M/32) = 1024 blocks.
// Chunk-final cf computed in-register (each block covers its 128 cols).
// ---------------------------------------------------------------------------
__global__ __launch_bounds__(256)
void gemm1_fused(const float* __restrict__ A,      // u [M,K] fp32
                 const ushort_t* __restrict__ B,   // Bw16 [NS,K] bf16
                 float* __restrict__ Bu,           // [M,NS] fp32
                 const float* __restrict__ ll,     // [NS]
                 float* __restrict__ cf)           // [BATCH,NCH,NS]
{
    const int K = DM;
    __shared__ __align__(16) ushort_t As[2][32*BK1];    // 2 x 4 KB
    __shared__ __align__(16) ushort_t Bs[2][BN1*BK1];   // 2 x 16 KB

    const int tid  = threadIdx.x;
    const int lane = tid & 63;
    const int wave = tid >> 6;       // n-slice: cols wave*32..wave*32+31
    const int n0   = blockIdx.x * BN1;
    const int m0   = blockIdx.y * 32;

    const int fr = lane & 15;
    const int fq = lane >> 4;

    // A staging: 32x64 fp32 = 512 float4 chunks, 2/thread; swizzled ds_write.
    int arow[2], ac4[2], aoff[2];
    #pragma unroll
    for (int j = 0; j < 2; ++j) {
        int cid = j*256 + tid;
        arow[j] = cid >> 4;
        ac4[j]  = (cid & 15) * 4;
        aoff[j] = arow[j]*BK1 + (((ac4[j] >> 3) ^ (arow[j] & 7)) * 8) + (ac4[j] & 4);
    }
    // B staging: 128x64 bf16 = 1024 x16B chunks, 4/thread; linear LDS dst,
    // inverse-swizzled global source column.
    int brow[4], bcs[4];
    #pragma unroll
    for (int j = 0; j < 4; ++j) {
        int cid = j*256 + tid;
        brow[j] = cid >> 3;
        bcs[j]  = ((cid & 7) ^ (brow[j] & 7)) * 8;
    }

    f32x4 acc[2][2] = {};   // [mi][ni] : m = mi*16.., n = wave*32 + ni*16..
    v4f areg0[2], areg1[2];

    const int NIT = K / BK1;   // 16 (even)

    // ---- prologue: A k=0, B k=0, A k=1 ----
    #pragma unroll
    for (int j = 0; j < 2; ++j)
        areg0[j] = *(const v4f*)&A[(size_t)(m0 + arow[j])*K + ac4[j]];
    #pragma unroll
    for (int j = 0; j < 4; ++j)
        gl_lds16(&B[(size_t)(n0 + brow[j])*K + bcs[j]], &Bs[0][(j*256 + tid)*8]);
    #pragma unroll
    for (int j = 0; j < 2; ++j)
        areg1[j] = *(const v4f*)&A[(size_t)(m0 + arow[j])*K + BK1 + ac4[j]];

    // one step per macro call; P = buffer parity (compile-time)
    #define G1_STEP(IT, P, AREG)                                               \
    {                                                                          \
        _Pragma("unroll")                                                      \
        for (int j = 0; j < 2; ++j)                                            \
            *(v4bf*)&As[P][aoff[j]] = __builtin_convertvector(AREG[j], v4bf);  \
        __syncthreads();                                                       \
        if ((IT) + 2 < NIT) {                                                  \
            const int k2 = ((IT) + 2) * BK1;                                   \
            _Pragma("unroll")                                                  \
            for (int j = 0; j < 2; ++j)                                        \
                AREG[j] = *(const v4f*)&A[(size_t)(m0 + arow[j])*K + k2 + ac4[j]]; \
        }                                                                      \
        if ((IT) + 1 < NIT) {                                                  \
            const int k1 = ((IT) + 1) * BK1;                                   \
            _Pragma("unroll")                                                  \
            for (int j = 0; j < 4; ++j)                                        \
                gl_lds16(&B[(size_t)(n0 + brow[j])*K + k1 + bcs[j]],           \
                         &Bs[(P)^1][(j*256 + tid)*8]);                         \
        }                                                                      \
        _Pragma("unroll")                                                      \
        for (int kk = 0; kk < 2; ++kk) {                                       \
            v8bf af[2], bf[2];                                                 \
            _Pragma("unroll")                                                  \
            for (int mi = 0; mi < 2; ++mi) {                                   \
                const int r  = mi*16 + fr;                                     \
                const int ch = (kk*4 + fq) ^ (r & 7);                          \
                af[mi] = *reinterpret_cast<const v8bf*>(&As[P][r*BK1 + ch*8]); \
            }                                                                  \
            _Pragma("unroll")                                                  \
            for (int ni = 0; ni < 2; ++ni) {                                   \
                const int r  = wave*32 + ni*16 + fr;                           \
                const int ch = (kk*4 + fq) ^ (r & 7);                          \
                bf[ni] = *reinterpret_cast<const v8bf*>(&Bs[P][r*BK1 + ch*8]); \
            }                                                                  \
            _Pragma("unroll")                                                  \
            for (int mi = 0; mi < 2; ++mi)                                     \
                _Pragma("unroll")                                              \
                for (int ni = 0; ni < 2; ++ni)                                 \
                    acc[mi][ni] = __builtin_amdgcn_mfma_f32_16x16x32_bf16(     \
                                      af[mi], bf[ni], acc[mi][ni], 0, 0, 0);   \
        }                                                                      \
    }

    for (int it = 0; it < NIT; it += 2) {
        G1_STEP(it,     0, areg0);
        G1_STEP(it + 1, 1, areg1);
    }
    #undef G1_STEP

    // ---- write Bu. C/D layout: col=lane&15, row=(lane>>4)*4+reg ----
    #pragma unroll
    for (int mi = 0; mi < 2; ++mi) {
        #pragma unroll
        for (int ni = 0; ni < 2; ++ni) {
            const int col = n0 + wave*32 + ni*16 + fr;
            #pragma unroll
            for (int r = 0; r < 4; ++r)
                Bu[(size_t)(m0 + mi*16 + fq*4 + r)*NS + col] = acc[mi][ni][r];
        }
    }

    // ---- chunk final: cf[b,c,n] = sum_t lam^(31-t) Bu[t,n]; block = chunk ----
    const int b_idx = m0 >> 12;            // 4096 rows per batch
    const int c_idx = (m0 & 4095) >> 5;    // 32 rows per chunk

    #pragma unroll
    for (int ni = 0; ni < 2; ++ni) {
        const int col = n0 + wave*32 + ni*16 + fr;
        const float l1  = sigm(ll[col]);
        const float l2  = l1*l1;
        const float l4  = l2*l2;
        const float l8  = l4*l4;
        const float l16 = l8*l8;
        float f = 0.0f;
        #pragma unroll
        for (int mi = 0; mi < 2; ++mi) {
            float w = powk(28 - mi*16 - fq*4, l1, l2, l4, l8, l16);
            f = fmaf(w, acc[mi][ni][3], f);
            w *= l1; f = fmaf(w, acc[mi][ni][2], f);
            w *= l1; f = fmaf(w, acc[mi][ni][1], f);
            w *= l1; f = fmaf(w, acc[mi][ni][0], f);
        }
        f += __shfl_xor(f, 16, 64);
        f += __shfl_xor(f, 32, 64);
        if (fq == 0)
            cf[((size_t)b_idx*NCH + c_idx)*NS + col] = f;
    }
}

// ---------------------------------------------------------------------------
// GEMM2+scan fused, 32-row blocks (1 chunk), 256 thr, grid 512.
//   1) v[32] = Bu column (coalesced per row) -> registers, issued first so
//      HBM latency hides under the carry Horner (no LDS staging).
//   2) carry Horner over cf (L2-resident), scan replay -> swizzled bf16 hs
//      in LDS (16 KB). hs never touches HBM.
//   3) GEMM vs Cw in 8 column panels of 128, BK=64 dbuf (32 KB), swizzled.
// LDS total 48 KB -> 3 blocks/CU.
// ---------------------------------------------------------------------------
__global__ __launch_bounds__(256)
void gemm2_scan(const float* __restrict__ Bu,     // [M,NS] fp32
                const ushort_t* __restrict__ Cw,  // Cw16 [DM,NS] bf16
                const float* __restrict__ ll,     // [NS]
                const float* __restrict__ cf,     // [BATCH,NCH,NS]
                float* __restrict__ Y,            // [M,DM] fp32
                const float* __restrict__ Dvec,
                const float* __restrict__ U)
{
    __shared__ __align__(16) ushort_t hsS[BM2*NS];        // 16 KB (swizzled)
    __shared__ __align__(16) ushort_t Bsw[2][128*BK2];    // 32 KB

    const int tid  = threadIdx.x;
    const int lane = tid & 63;
    const int wave = tid >> 6;       // n-quadrant within panel: cols wave*32..
    const int fr = lane & 15;
    const int fq = lane >> 4;
    const int m0 = blockIdx.x * BM2;
    const int n  = tid;              // state column 0..255

    // ---- 1) Bu column -> regs (issued first; 32 coalesced rows) ----
    const float* bp = Bu + (size_t)m0*NS + n;
    float v[CL];
    #pragma unroll
    for (int t = 0; t < CL; ++t)
        v[t] = bp[(size_t)t*NS];

    // ---- prefetch first Cw panel k-step (pre-swizzled source, linear dst) ----
    #define STAGE_B(g, buf)                                                    \
        {                                                                      \
            const int p_ = (g) >> 2, ks_ = (g) & 3;                            \
            _Pragma("unroll")                                                  \
            for (int jj = 0; jj < 4; ++jj) {                                   \
                const int cid = jj*256 + tid;                                  \
                const int row_ = cid >> 3, kch_ = cid & 7;                     \
                const int koff_ = ks_*BK2 + ((kch_ ^ (row_ & 7)) * 8);         \
                gl_lds16(&Cw[(size_t)(p_*128 + row_)*NS + koff_],              \
                         &Bsw[buf][cid*8]);                                    \
            }                                                                  \
        }
    STAGE_B(0, 0);

    // ---- 2) carry Horner over cf ----
    const int b_idx = m0 >> 12;
    const int cG    = (m0 & 4095) >> 5;    // need chunks [0, cG)
    const float lam = sigm(ll[n]);
    float lamL = lam;
    #pragma unroll
    for (int i = 0; i < 5; ++i) lamL *= lamL;   // lam^32

    const float* cfb = cf + (size_t)b_idx*NCH*NS + n;
    float x = 0.0f;
    int cc = 0;
    for (; cc + 16 <= cG; cc += 16) {
        float vv[16];
        #pragma unroll
        for (int j = 0; j < 16; ++j) vv[j] = cfb[(size_t)(cc + j)*NS];
        #pragma unroll
        for (int j = 0; j < 16; ++j) x = fmaf(lamL, x, vv[j]);
    }
    for (; cc < cG; ++cc) x = fmaf(lamL, x, cfb[(size_t)cc*NS]);

    // ---- scan replay; hs written bf16 with (row&7) chunk-XOR swizzle ----
    float h = x;
    #pragma unroll
    for (int t = 0; t < CL; ++t) {
        h = fmaf(lam, h, v[t]);
        hsS[t*NS + (((n >> 3) ^ (t & 7)) << 3) + (n & 7)] = f2bf(h);
    }
    __syncthreads();   // hs complete; Bsw[0] staged (drained by barrier)

    // ---- 3) GEMM: 8 panels x (K=256 in 4 steps of BK2=64), dbuf ----
    int g = 0;
    for (int p = 0; p < 8; ++p) {
        f32x4 acc[2][2] = {};
        for (int ks = 0; ks < 4; ++ks, ++g) {
            const int cur = g & 1;
            if (g) __syncthreads();
            if (g + 1 < 32) STAGE_B(g + 1, cur ^ 1);

            #pragma unroll
            for (int kk = 0; kk < 2; ++kk) {
                v8bf af[2], bf[2];
                #pragma unroll
                for (int mi = 0; mi < 2; ++mi) {
                    const int r  = mi*16 + fr;
                    const int ch = (ks*8 + kk*4 + fq) ^ (r & 7);
                    af[mi] = *reinterpret_cast<const v8bf*>(&hsS[r*NS + ch*8]);
                }
                #pragma unroll
                for (int ni = 0; ni < 2; ++ni) {
                    const int rn = wave*32 + ni*16 + fr;
                    const int ch = (kk*4 + fq) ^ (rn & 7);
                    bf[ni] = *reinterpret_cast<const v8bf*>(&Bsw[cur][rn*BK2 + ch*8]);
                }
                #pragma unroll
                for (int mi = 0; mi < 2; ++mi)
                    #pragma unroll
                    for (int ni = 0; ni < 2; ++ni)
                        acc[mi][ni] = __builtin_amdgcn_mfma_f32_16x16x32_bf16(
                                          af[mi], bf[ni], acc[mi][ni], 0, 0, 0);
            }
        }
        // panel epilogue (C/D layout: col=lane&15, row=fq*4+reg)
        #pragma unroll
        for (int ni = 0; ni < 2; ++ni) {
            const int gcol = p*128 + wave*32 + ni*16 + fr;
            const float d = Dvec[gcol];
            #pragma unroll
            for (int mi = 0; mi < 2; ++mi) {
                #pragma unroll
                for (int r = 0; r < 4; ++r) {
                    const int grow = m0 + mi*16 + fq*4 + r;
                    const size_t idx = (size_t)grow*DM + gcol;
                    float vo = acc[mi][ni][r];
                    if (d != 0.0f) vo = fmaf(d, U[idx], vo);   // no load when D==0
                    Y[idx] = vo;
                }
            }
        }
    }
    #undef STAGE_B
}

// ---------------------------------------------------------------------------
__global__ __launch_bounds__(256)
void cvt_w(const float4* __restrict__ Bw, const float4* __restrict__ Cw,
           ushort_t* __restrict__ Bo, ushort_t* __restrict__ Co)
{
    const int i = blockIdx.x * 256 + threadIdx.x;
    const float4* src = blockIdx.y ? Cw : Bw;
    ushort_t*     dst = blockIdx.y ? Co : Bo;
    float4 v = src[i];
    ushort4 o;
    o.x = f2bf(v.x); o.y = f2bf(v.y); o.z = f2bf(v.z); o.w = f2bf(v.w);
    *(ushort4*)&dst[4*(size_t)i] = o;
}

// ---------------------------------------------------------------------------
extern "C" void kernel_launch(void* const* d_in, const int* in_sizes, int n_in,
                              void* d_out, int out_size, void* d_ws, size_t ws_size,
                              hipStream_t stream) {
    const float* u          = (const float*)d_in[0];
    const float* log_lambda = (const float*)d_in[1];
    const float* B_w        = (const float*)d_in[2];
    const float* C_w        = (const float*)d_in[3];
    const float* Dv         = (const float*)d_in[4];
    float* y  = (float*)d_out;

    char* w = (char*)d_ws;
    float*    Bu   = (float*)w;                        // 16.78 MB
    ushort_t* Bw16 = (ushort_t*)(w + 16777216);        // 512 KB
    ushort_t* Cw16 = (ushort_t*)(w + 17301504);        // 512 KB
    float*    cf   = (float*)(w + 17825792);           // 512 KB

    dim3 blk(256);

    // 0) weight conversions
    cvt_w<<<dim3(256, 2), blk, 0, stream>>>((const float4*)B_w, (const float4*)C_w,
                                            Bw16, Cw16);

    // 1) Bu = u . B_w^T (32x128 tiles, 4 blocks/CU), fused chunk finals
    gemm1_fused<<<dim3(2, MROWS/32), blk, 0, stream>>>(u, Bw16, Bu, log_lambda, cf);

    // 2) fused scan + y = hs . C_w^T + D*u
    gemm2_scan<<<dim3(MROWS/BM2), blk, 0, stream>>>(
        Bu, Cw16, log_lambda, cf, y, Dv, u);
}